// Round 14
// baseline (157.083 us; speedup 1.0000x reference)
//
#include <hip/hip_runtime.h>
#include <math.h>

#define D_MODEL 512
#define NHEADS  8
#define DH      64
#define LSEQ    4096
#define NB      2
#define M_TOT   (NB * LSEQ)   // 8192
#define NSPLIT  2
#define KHALF   (LSEQ / NSPLIT)

typedef __attribute__((ext_vector_type(8))) short bf16x8;   // 8 bf16 = 4 VGPRs
typedef __attribute__((ext_vector_type(4))) float f32x4;
typedef __attribute__((ext_vector_type(8))) unsigned short ushort8v;

#define MFMA16(a, b, c) __builtin_amdgcn_mfma_f32_16x16x32_bf16(a, b, c, 0, 0, 0)

__device__ __forceinline__ ushort f2bf(float x) {
    unsigned u = __builtin_bit_cast(unsigned, x);
    u += 0x7fffu + ((u >> 16) & 1u);    // RNE
    return (ushort)(u >> 16);
}

__device__ __forceinline__ float bf2f(ushort u) {
    unsigned v = ((unsigned)u) << 16;
    return __builtin_bit_cast(float, v);
}

// packed f32x2 -> bf16x2 (lo = a, hi = b), single HW instruction, RNE
__device__ __forceinline__ unsigned cvt_pk_bf16(float a, float b) {
    unsigned r;
    asm("v_cvt_pk_bf16_f32 %0, %1, %2" : "=v"(r) : "v"(a), "v"(b));
    return r;
}

__device__ __forceinline__ float fexp2(float x) {
#if __has_builtin(__builtin_amdgcn_exp2f)
    return __builtin_amdgcn_exp2f(x);
#else
    return exp2f(x);
#endif
}

__device__ __forceinline__ void gload16(const void* g, void* l) {
    __builtin_amdgcn_global_load_lds(
        (const __attribute__((address_space(1))) unsigned*)g,
        (__attribute__((address_space(3))) unsigned*)l, 16, 0, 0);
}

// ---------------------------------------------------------------------------
// Cast fp32 -> bf16 (X and the four weight matrices).  R10-proven.
// ---------------------------------------------------------------------------
__global__ __launch_bounds__(256) void cast_all(
    const float* __restrict__ X,  const float* __restrict__ Wq,
    const float* __restrict__ Wk, const float* __restrict__ Wv,
    const float* __restrict__ Wo,
    ushort* __restrict__ Xb,  ushort* __restrict__ Wqb,
    ushort* __restrict__ Wkb, ushort* __restrict__ Wvb,
    ushort* __restrict__ Wob)
{
    const int seg = blockIdx.y;
    const float* src = seg == 0 ? X : seg == 1 ? Wq : seg == 2 ? Wk
                      : seg == 3 ? Wv : Wo;
    ushort* dst = seg == 0 ? Xb : seg == 1 ? Wqb : seg == 2 ? Wkb
                 : seg == 3 ? Wvb : Wob;
    const int n = (seg == 0) ? M_TOT * D_MODEL : D_MODEL * D_MODEL;
    const int idx = (blockIdx.x * 256 + threadIdx.x) * 8;
    if (idx >= n) return;
    float4 a = *(const float4*)(src + idx);
    float4 b = *(const float4*)(src + idx + 4);
    ushort8v o;
    o[0] = f2bf(a.x); o[1] = f2bf(a.y); o[2] = f2bf(a.z); o[3] = f2bf(a.w);
    o[4] = f2bf(b.x); o[5] = f2bf(b.y); o[6] = f2bf(b.z); o[7] = f2bf(b.w);
    *(ushort8v*)(dst + idx) = o;
}

// ---------------------------------------------------------------------------
// bf16 MFMA GEMM core (R10-proven): BM=BN=128, BK=64, 4 waves, 2-barrier
// loop, global_load_lds width-16 staging both operands, linear LDS.
// ---------------------------------------------------------------------------
__device__ __forceinline__ void gemm_core(
    const ushort* __restrict__ A, const ushort* __restrict__ Bw,
    ushort (*Alds)[64], ushort (*Blds)[64], f32x4 acc[4][4],
    int m0, int n0, int w, int lg, int lr)
{
    const int tid = threadIdx.x;
    const int wr = w >> 1, wc = w & 1;
    const int srow = tid >> 3;          // 0..31
    const int scol = (tid & 7) * 8;     // bf16 col (16B per lane)

    for (int k0 = 0; k0 < D_MODEL; k0 += 64) {
        __syncthreads();
        #pragma unroll
        for (int i = 0; i < 4; ++i) {
            gload16(A  + (size_t)(m0 + i * 32 + srow) * D_MODEL + k0 + scol,
                    (char*)Alds + i * 4096 + w * 1024);
            gload16(Bw + (size_t)(n0 + i * 32 + srow) * D_MODEL + k0 + scol,
                    (char*)Blds + i * 4096 + w * 1024);
        }
        __syncthreads();
        #pragma unroll
        for (int kk = 0; kk < 2; ++kk) {
            bf16x8 af[4], bfr[4];
            #pragma unroll
            for (int i = 0; i < 4; ++i)
                af[i] = *(const bf16x8*)&Alds[wr * 64 + 16 * i + lr][kk * 32 + 8 * lg];
            #pragma unroll
            for (int j = 0; j < 4; ++j)
                bfr[j] = *(const bf16x8*)&Blds[wc * 64 + 16 * j + lr][kk * 32 + 8 * lg];
            #pragma unroll
            for (int i = 0; i < 4; ++i)
                #pragma unroll
                for (int j = 0; j < 4; ++j)
                    acc[i][j] = MFMA16(af[i], bfr[j], acc[i][j]);
        }
    }
}

__global__ __launch_bounds__(256) void gemm_qkv(
    const ushort* __restrict__ Xb,
    const ushort* __restrict__ Wqb, const ushort* __restrict__ Wkb,
    const ushort* __restrict__ Wvb,
    ushort* __restrict__ Qb, ushort* __restrict__ Kb, ushort* __restrict__ Vtb)
{
    __shared__ __align__(16) ushort Alds[128][64];
    __shared__ __align__(16) ushort Blds[128][64];

    const int mode = blockIdx.z;
    const ushort* Bw = mode == 0 ? Wqb : mode == 1 ? Wkb : Wvb;

    const int tid = threadIdx.x;
    const int w = tid >> 6, l = tid & 63;
    const int lg = l >> 4, lr = l & 15;
    const int wr = w >> 1, wc = w & 1;
    const int m0 = blockIdx.x * 128;
    const int n0 = blockIdx.y * 128;

    f32x4 acc[4][4];
    #pragma unroll
    for (int i = 0; i < 4; ++i)
        #pragma unroll
        for (int j = 0; j < 4; ++j) acc[i][j] = (f32x4){0.f, 0.f, 0.f, 0.f};

    gemm_core(Xb, Bw, Alds, Blds, acc, m0, n0, w, lg, lr);

    if (mode < 2) {
        const float scale = (mode == 0) ? 0.125f * 1.44269504088896f : 1.0f;
        ushort* Yb = (mode == 0) ? Qb : Kb;
        #pragma unroll
        for (int i = 0; i < 4; ++i) {
            const int mb = m0 + wr * 64 + 16 * i + 4 * lg;
            const int b = mb >> 12, lq = mb & 4095;
            #pragma unroll
            for (int j = 0; j < 4; ++j) {
                const int ng = n0 + wc * 64 + 16 * j + lr;
                const int h = ng >> 6, dh = ng & 63;
                ushort* Yp = Yb + ((size_t)(b * NHEADS + h) * LSEQ + lq) * DH + dh;
                #pragma unroll
                for (int r = 0; r < 4; ++r)
                    Yp[(size_t)r * DH] = f2bf(acc[i][j][r] * scale);
            }
        }
    } else {
        #pragma unroll
        for (int i = 0; i < 4; ++i) {
            const int mb = m0 + wr * 64 + 16 * i + 4 * lg;
            const int b = mb >> 12, lq = mb & 4095;
            #pragma unroll
            for (int j = 0; j < 4; ++j) {
                const int ng = n0 + wc * 64 + 16 * j + lr;
                const int h = ng >> 6, dh = ng & 63;
                ushort4 w4;
                w4.x = f2bf(acc[i][j][0]); w4.y = f2bf(acc[i][j][1]);
                w4.z = f2bf(acc[i][j][2]); w4.w = f2bf(acc[i][j][3]);
                *(ushort4*)(Vtb + ((size_t)(b * NHEADS + h) * DH + dh) * LSEQ + lq) = w4;
            }
        }
    }
}

__global__ __launch_bounds__(256) void gemm_wo(
    const ushort* __restrict__ Cb, const ushort* __restrict__ Wob,
    float* __restrict__ out)
{
    __shared__ __align__(16) ushort Alds[128][64];
    __shared__ __align__(16) ushort Blds[128][64];

    const int tid = threadIdx.x;
    const int w = tid >> 6, l = tid & 63;
    const int lg = l >> 4, lr = l & 15;
    const int wr = w >> 1, wc = w & 1;
    const int m0 = blockIdx.x * 128;
    const int n0 = blockIdx.y * 128;

    f32x4 acc[4][4];
    #pragma unroll
    for (int i = 0; i < 4; ++i)
        #pragma unroll
        for (int j = 0; j < 4; ++j) acc[i][j] = (f32x4){0.f, 0.f, 0.f, 0.f};

    gemm_core(Cb, Wob, Alds, Blds, acc, m0, n0, w, lg, lr);

    #pragma unroll
    for (int i = 0; i < 4; ++i) {
        const int mb = m0 + wr * 64 + 16 * i + 4 * lg;
        #pragma unroll
        for (int j = 0; j < 4; ++j) {
            const int ng = n0 + wc * 64 + 16 * j + lr;
            float* Yp = out + (size_t)mb * D_MODEL + ng;
            #pragma unroll
            for (int r = 0; r < 4; ++r)
                Yp[(size_t)r * D_MODEL] = acc[i][j][r];
        }
    }
}

// ---------------------------------------------------------------------------
// Flash attention (R10 base): bf16 MFMA, swapped QK^T, static-max softmax,
// QBLK=256 (4 waves x 64 q-rows), KV-split x2, Plds round-trip PV, pad-68.
// NEW vs R10 (contained, no layout change):
//  - lsum computed on the MFMA pipe: one extra PV MFMA per (u,vh) with a
//    constant all-ones B fragment (register splat, no LDS/DS cost) gives
//    exact per-q row sums in o5[u]; deletes 64 VALU adds/lane/tile and the
//    epilogue shuffle reduction.  Denominator uses the same bf16-rounded P
//    as the numerator (self-consistent).
//  - s_setprio(1) around both MFMA clusters (T5; 2 phase-offset blocks/CU).
// ---------------------------------------------------------------------------
#define QBLK 256
#define KBLK 64

__global__ __launch_bounds__(256) void flash_mfma(
    const ushort* __restrict__ Q, const ushort* __restrict__ K,
    const ushort* __restrict__ Vt, ushort* __restrict__ Op,
    float* __restrict__ Ls)
{
    __shared__ __align__(16) ushort Klds[64][68];    // [key][dh]
    __shared__ __align__(16) ushort Vlds[64][68];    // [dh][key]
    __shared__ __align__(16) ushort Plds[256][68];   // [q][key]

    const int tid = threadIdx.x;
    const int w  = tid >> 6;
    const int l  = tid & 63;
    const int lg = l >> 4;
    const int lr = l & 15;

    const int bh = blockIdx.y;
    const int q0 = blockIdx.x * QBLK;
    const int z  = blockIdx.z;
    const int kt0 = z * KHALF;

    const bf16x8 vones = {(short)0x3F80, (short)0x3F80, (short)0x3F80,
                          (short)0x3F80, (short)0x3F80, (short)0x3F80,
                          (short)0x3F80, (short)0x3F80};   // bf16 1.0 x8

    bf16x8 qa[4][2];
    #pragma unroll
    for (int u = 0; u < 4; ++u) {
        const ushort* qp = Q + ((size_t)bh * LSEQ + q0 + 64 * w + 16 * u + lr) * DH + 8 * lg;
        qa[u][0] = *(const bf16x8*)(qp);
        qa[u][1] = *(const bf16x8*)(qp + 32);
    }

    f32x4 o4[4][4];
    f32x4 o5[4];   // row-sum accumulator (ones-column PV)
    #pragma unroll
    for (int u = 0; u < 4; ++u) {
        #pragma unroll
        for (int ot = 0; ot < 4; ++ot) o4[u][ot] = (f32x4){0.f, 0.f, 0.f, 0.f};
        o5[u] = (f32x4){0.f, 0.f, 0.f, 0.f};
    }

    const int srow = tid >> 2;            // 0..63
    const int scol = (tid & 3) << 4;      // 0,16,32,48
    const ushort* Kp = K  + (size_t)bh * LSEQ * DH;
    const ushort* Vp = Vt + (size_t)bh * DH * LSEQ;

    uint4 kA, kB, vA, vB;
    {
        const ushort* ks = Kp + (size_t)(kt0 + srow) * DH + scol;
        const ushort* vs = Vp + (size_t)srow * LSEQ + kt0 + scol;
        kA = *(const uint4*)(ks); kB = *(const uint4*)(ks + 8);
        vA = *(const uint4*)(vs); vB = *(const uint4*)(vs + 8);
    }

    for (int kt = kt0; kt < kt0 + KHALF; kt += KBLK) {
        __syncthreads();
        *(uint4*)&Klds[srow][scol] = kA;  *(uint4*)&Klds[srow][scol + 8] = kB;
        *(uint4*)&Vlds[srow][scol] = vA;  *(uint4*)&Vlds[srow][scol + 8] = vB;
        __syncthreads();

        if (kt + KBLK < kt0 + KHALF) {
            const ushort* ks = Kp + (size_t)(kt + KBLK + srow) * DH + scol;
            const ushort* vs = Vp + (size_t)srow * LSEQ + (kt + KBLK) + scol;
            kA = *(const uint4*)(ks); kB = *(const uint4*)(ks + 8);
            vA = *(const uint4*)(vs); vB = *(const uint4*)(vs + 8);
        }

        // ---- S^T = K Q^T : k-reads shared across the 4 q-subtiles ----
        f32x4 s[4][4];
        __builtin_amdgcn_s_setprio(1);
        #pragma unroll
        for (int kt2 = 0; kt2 < 4; ++kt2) {
            bf16x8 k0 = *(const bf16x8*)&Klds[kt2 * 16 + lr][8 * lg];
            bf16x8 k1 = *(const bf16x8*)&Klds[kt2 * 16 + lr][32 + 8 * lg];
            #pragma unroll
            for (int u = 0; u < 4; ++u) {
                f32x4 z4 = (f32x4){0.f, 0.f, 0.f, 0.f};
                s[u][kt2] = MFMA16(k1, qa[u][1], MFMA16(k0, qa[u][0], z4));
            }
        }
        __builtin_amdgcn_s_setprio(0);

        // ---- static-max softmax: p = 2^s; P -> Plds (bf16) ----
        #pragma unroll
        for (int u = 0; u < 4; ++u) {
            #pragma unroll
            for (int kt2 = 0; kt2 < 4; ++kt2) {
                const float p0 = fexp2(s[u][kt2][0]);
                const float p1 = fexp2(s[u][kt2][1]);
                const float p2 = fexp2(s[u][kt2][2]);
                const float p3 = fexp2(s[u][kt2][3]);
                uint2 pw;
                pw.x = cvt_pk_bf16(p0, p1);
                pw.y = cvt_pk_bf16(p2, p3);
                *(uint2*)&Plds[64 * w + 16 * u + lr][kt2 * 16 + 4 * lg] = pw;
            }
        }

        // ---- O += P V ; row-sums += P * ones (MFMA pipe) ----
        __builtin_amdgcn_s_setprio(1);
        #pragma unroll
        for (int vh = 0; vh < 2; ++vh) {
            bf16x8 pa[4];
            #pragma unroll
            for (int u = 0; u < 4; ++u)
                pa[u] = *(const bf16x8*)&Plds[64 * w + 16 * u + lr][32 * vh + 8 * lg];
            #pragma unroll
            for (int ot = 0; ot < 4; ++ot) {
                bf16x8 vv = *(const bf16x8*)&Vlds[16 * ot + lr][32 * vh + 8 * lg];
                #pragma unroll
                for (int u = 0; u < 4; ++u)
                    o4[u][ot] = MFMA16(pa[u], vv, o4[u][ot]);
            }
            #pragma unroll
            for (int u = 0; u < 4; ++u)
                o5[u] = MFMA16(pa[u], vones, o5[u]);
        }
        __builtin_amdgcn_s_setprio(0);
    }

    // ---- epilogue: unnormalized bf16 O-partial + row sums from o5 ----
    const int b = bh >> 3, h = bh & 7;
    ushort* Opz = Op + (size_t)z * M_TOT * D_MODEL;
    #pragma unroll
    for (int u = 0; u < 4; ++u) {
        if (lr == 0) {   // o5[u][r] = full row sum for q = 16u + 4lg + r
            #pragma unroll
            for (int r = 0; r < 4; ++r)
                Ls[((size_t)z * NB * NHEADS + bh) * LSEQ
                   + q0 + 64 * w + 16 * u + 4 * lg + r] = o5[u][r];
        }
        #pragma unroll
        for (int r = 0; r < 4; ++r) {
            const int qrow = q0 + 64 * w + 16 * u + 4 * lg + r;
            ushort* op = Opz + ((size_t)b * LSEQ + qrow) * D_MODEL + h * DH + lr;
            #pragma unroll
            for (int ot = 0; ot < 4; ++ot)
                op[16 * ot] = f2bf(o4[u][ot][r]);
        }
    }
}

// ---------------------------------------------------------------------------
// Combine the two KV-split partials: Cb = (O0 + O1) / (l0 + l1), bf16.
// ---------------------------------------------------------------------------
__global__ __launch_bounds__(256) void combine(
    const ushort* __restrict__ Op, const float* __restrict__ Ls,
    ushort* __restrict__ Cb)
{
    const int idx = blockIdx.x * 256 + threadIdx.x;   // one 8-elem chunk
    const int row = idx >> 6;                         // 0..M_TOT-1
    const int col0 = (idx & 63) << 3;
    const int b = row >> 12, lq = row & 4095;
    const int h = col0 >> 6;
    const int bh = b * NHEADS + h;

    const float l0 = Ls[(size_t)bh * LSEQ + lq];
    const float l1 = Ls[((size_t)NB * NHEADS + bh) * LSEQ + lq];
    const float inv = 1.0f / (l0 + l1);

    const size_t off = (size_t)row * D_MODEL + col0;
    ushort8v a0 = *(const ushort8v*)(Op + off);
    ushort8v a1 = *(const ushort8v*)(Op + (size_t)M_TOT * D_MODEL + off);
    ushort8v o;
    #pragma unroll
    for (int i = 0; i < 8; ++i)
        o[i] = f2bf((bf2f(a0[i]) + bf2f(a1[i])) * inv);
    *(ushort8v*)(Cb + off) = o;
}

// ---------------------------------------------------------------------------
extern "C" void kernel_launch(void* const* d_in, const int* in_sizes, int n_in,
                              void* d_out, int out_size, void* d_ws, size_t ws_size,
                              hipStream_t stream)
{
    const float* X  = (const float*)d_in[0];
    const float* Wq = (const float*)d_in[1];
    const float* Wk = (const float*)d_in[2];
    const float* Wv = (const float*)d_in[3];
    const float* Wo = (const float*)d_in[4];
    float* out = (float*)d_out;

    char* ws = (char*)d_ws;
    const size_t szX = (size_t)M_TOT * D_MODEL * 2;       // 8.39 MB
    const size_t szW = (size_t)D_MODEL * D_MODEL * 2;     // 0.52 MB
    ushort* Xb  = (ushort*)(ws);
    ushort* Wqb = (ushort*)(ws + szX);
    ushort* Wkb = (ushort*)(ws + szX + szW);
    ushort* Wvb = (ushort*)(ws + szX + 2 * szW);
    ushort* Wob = (ushort*)(ws + szX + 3 * szW);
    ushort* Qb  = (ushort*)(ws + szX + 4 * szW);
    ushort* Kb  = (ushort*)(ws + 2 * szX + 4 * szW);
    ushort* Vtb = (ushort*)(ws + 3 * szX + 4 * szW);
    ushort* Opb = (ushort*)(ws + 4 * szX + 4 * szW);      // 2 x 8.39 MB
    float*  Lsb = (float*) (ws + 6 * szX + 4 * szW);      // 0.52 MB
    ushort* Cbb = (ushort*)(ws + 6 * szX + 4 * szW
                            + (size_t)NSPLIT * NB * NHEADS * LSEQ * 4);

    dim3 gc(M_TOT * D_MODEL / (256 * 8), 5);
    cast_all<<<gc, 256, 0, stream>>>(X, Wq, Wk, Wv, Wo, Xb, Wqb, Wkb, Wvb, Wob);

    dim3 gq(M_TOT / 128, D_MODEL / 128, 3);
    gemm_qkv<<<gq, 256, 0, stream>>>(Xb, Wqb, Wkb, Wvb, Qb, Kb, Vtb);

    dim3 gf(LSEQ / QBLK, NB * NHEADS, NSPLIT);
    flash_mfma<<<gf, 256, 0, stream>>>(Qb, Kb, Vtb, Opb, Lsb);

    dim3 gm(M_TOT * D_MODEL / (256 * 8));
    combine<<<gm, 256, 0, stream>>>(Opb, Lsb, Cbb);

    dim3 go(M_TOT / 128, D_MODEL / 128);
    gemm_wo<<<go, 256, 0, stream>>>(Cbb, Wob, out);
}

// Round 15
// 146.919 us; speedup vs baseline: 1.0692x; 1.0692x over previous
//
#include <hip/hip_runtime.h>
#include <math.h>

#define D_MODEL 512
#define NHEADS  8
#define DH      64
#define LSEQ    4096
#define NB      2
#define M_TOT   (NB * LSEQ)   // 8192
#define NSPLIT  2
#define KHALF   (LSEQ / NSPLIT)

typedef __attribute__((ext_vector_type(8))) short bf16x8;   // 8 bf16 = 4 VGPRs
typedef __attribute__((ext_vector_type(4))) float f32x4;
typedef __attribute__((ext_vector_type(8))) unsigned short ushort8v;

#define MFMA16(a, b, c) __builtin_amdgcn_mfma_f32_16x16x32_bf16(a, b, c, 0, 0, 0)

__device__ __forceinline__ ushort f2bf(float x) {
    unsigned u = __builtin_bit_cast(unsigned, x);
    u += 0x7fffu + ((u >> 16) & 1u);    // RNE
    return (ushort)(u >> 16);
}

__device__ __forceinline__ float bf2f(ushort u) {
    unsigned v = ((unsigned)u) << 16;
    return __builtin_bit_cast(float, v);
}

// packed f32x2 -> bf16x2 (lo = a, hi = b), single HW instruction, RNE
__device__ __forceinline__ unsigned cvt_pk_bf16(float a, float b) {
    unsigned r;
    asm("v_cvt_pk_bf16_f32 %0, %1, %2" : "=v"(r) : "v"(a), "v"(b));
    return r;
}

__device__ __forceinline__ float fexp2(float x) {
#if __has_builtin(__builtin_amdgcn_exp2f)
    return __builtin_amdgcn_exp2f(x);
#else
    return exp2f(x);
#endif
}

__device__ __forceinline__ void gload16(const void* g, void* l) {
    __builtin_amdgcn_global_load_lds(
        (const __attribute__((address_space(1))) unsigned*)g,
        (__attribute__((address_space(3))) unsigned*)l, 16, 0, 0);
}

// ---------------------------------------------------------------------------
// Cast fp32 -> bf16 (X and the four weight matrices).
// ---------------------------------------------------------------------------
__global__ __launch_bounds__(256) void cast_all(
    const float* __restrict__ X,  const float* __restrict__ Wq,
    const float* __restrict__ Wk, const float* __restrict__ Wv,
    const float* __restrict__ Wo,
    ushort* __restrict__ Xb,  ushort* __restrict__ Wqb,
    ushort* __restrict__ Wkb, ushort* __restrict__ Wvb,
    ushort* __restrict__ Wob)
{
    const int seg = blockIdx.y;
    const float* src = seg == 0 ? X : seg == 1 ? Wq : seg == 2 ? Wk
                      : seg == 3 ? Wv : Wo;
    ushort* dst = seg == 0 ? Xb : seg == 1 ? Wqb : seg == 2 ? Wkb
                 : seg == 3 ? Wvb : Wob;
    const int n = (seg == 0) ? M_TOT * D_MODEL : D_MODEL * D_MODEL;
    const int idx = (blockIdx.x * 256 + threadIdx.x) * 8;
    if (idx >= n) return;
    float4 a = *(const float4*)(src + idx);
    float4 b = *(const float4*)(src + idx + 4);
    ushort8v o;
    o[0] = f2bf(a.x); o[1] = f2bf(a.y); o[2] = f2bf(a.z); o[3] = f2bf(a.w);
    o[4] = f2bf(b.x); o[5] = f2bf(b.y); o[6] = f2bf(b.z); o[7] = f2bf(b.w);
    *(ushort8v*)(dst + idx) = o;
}

// ---------------------------------------------------------------------------
// bf16 MFMA GEMM, m97-style: BM=BN=128, BK=64, 4 waves (2x2), 2-barrier loop,
// global_load_lds width-16 staging, linear LDS.
// ---------------------------------------------------------------------------
__device__ __forceinline__ void gemm_core(
    const ushort* __restrict__ A, const ushort* __restrict__ Bw,
    ushort (*Alds)[64], ushort (*Blds)[64], f32x4 acc[4][4],
    int m0, int n0, int w, int lg, int lr)
{
    const int tid = threadIdx.x;
    const int wr = w >> 1, wc = w & 1;
    const int srow = tid >> 3;          // 0..31
    const int scol = (tid & 7) * 8;     // bf16 col (16B per lane)

    for (int k0 = 0; k0 < D_MODEL; k0 += 64) {
        __syncthreads();
        #pragma unroll
        for (int i = 0; i < 4; ++i) {
            gload16(A  + (size_t)(m0 + i * 32 + srow) * D_MODEL + k0 + scol,
                    (char*)Alds + i * 4096 + w * 1024);
            gload16(Bw + (size_t)(n0 + i * 32 + srow) * D_MODEL + k0 + scol,
                    (char*)Blds + i * 4096 + w * 1024);
        }
        __syncthreads();
        #pragma unroll
        for (int kk = 0; kk < 2; ++kk) {
            bf16x8 af[4], bfr[4];
            #pragma unroll
            for (int i = 0; i < 4; ++i)
                af[i] = *(const bf16x8*)&Alds[wr * 64 + 16 * i + lr][kk * 32 + 8 * lg];
            #pragma unroll
            for (int j = 0; j < 4; ++j)
                bfr[j] = *(const bf16x8*)&Blds[wc * 64 + 16 * j + lr][kk * 32 + 8 * lg];
            #pragma unroll
            for (int i = 0; i < 4; ++i)
                #pragma unroll
                for (int j = 0; j < 4; ++j)
                    acc[i][j] = MFMA16(af[i], bfr[j], acc[i][j]);
        }
    }
}

__global__ __launch_bounds__(256) void gemm_qkv(
    const ushort* __restrict__ Xb,
    const ushort* __restrict__ Wqb, const ushort* __restrict__ Wkb,
    const ushort* __restrict__ Wvb,
    ushort* __restrict__ Qb, ushort* __restrict__ Kb, ushort* __restrict__ Vtb)
{
    __shared__ __align__(16) ushort Alds[128][64];
    __shared__ __align__(16) ushort Blds[128][64];

    const int mode = blockIdx.z;
    const ushort* Bw = mode == 0 ? Wqb : mode == 1 ? Wkb : Wvb;

    const int tid = threadIdx.x;
    const int w = tid >> 6, l = tid & 63;
    const int lg = l >> 4, lr = l & 15;
    const int wr = w >> 1, wc = w & 1;
    const int m0 = blockIdx.x * 128;
    const int n0 = blockIdx.y * 128;

    f32x4 acc[4][4];
    #pragma unroll
    for (int i = 0; i < 4; ++i)
        #pragma unroll
        for (int j = 0; j < 4; ++j) acc[i][j] = (f32x4){0.f, 0.f, 0.f, 0.f};

    gemm_core(Xb, Bw, Alds, Blds, acc, m0, n0, w, lg, lr);

    if (mode < 2) {
        const float scale = (mode == 0) ? 0.125f * 1.44269504088896f : 1.0f;
        ushort* Yb = (mode == 0) ? Qb : Kb;
        #pragma unroll
        for (int i = 0; i < 4; ++i) {
            const int mb = m0 + wr * 64 + 16 * i + 4 * lg;
            const int b = mb >> 12, lq = mb & 4095;
            #pragma unroll
            for (int j = 0; j < 4; ++j) {
                const int ng = n0 + wc * 64 + 16 * j + lr;
                const int h = ng >> 6, dh = ng & 63;
                ushort* Yp = Yb + ((size_t)(b * NHEADS + h) * LSEQ + lq) * DH + dh;
                #pragma unroll
                for (int r = 0; r < 4; ++r)
                    Yp[(size_t)r * DH] = f2bf(acc[i][j][r] * scale);
            }
        }
    } else {
        #pragma unroll
        for (int i = 0; i < 4; ++i) {
            const int mb = m0 + wr * 64 + 16 * i + 4 * lg;
            const int b = mb >> 12, lq = mb & 4095;
            #pragma unroll
            for (int j = 0; j < 4; ++j) {
                const int ng = n0 + wc * 64 + 16 * j + lr;
                const int h = ng >> 6, dh = ng & 63;
                ushort4 w4;
                w4.x = f2bf(acc[i][j][0]); w4.y = f2bf(acc[i][j][1]);
                w4.z = f2bf(acc[i][j][2]); w4.w = f2bf(acc[i][j][3]);
                *(ushort4*)(Vtb + ((size_t)(b * NHEADS + h) * DH + dh) * LSEQ + lq) = w4;
            }
        }
    }
}

__global__ __launch_bounds__(256) void gemm_wo(
    const ushort* __restrict__ Cb, const ushort* __restrict__ Wob,
    float* __restrict__ out)
{
    __shared__ __align__(16) ushort Alds[128][64];
    __shared__ __align__(16) ushort Blds[128][64];

    const int tid = threadIdx.x;
    const int w = tid >> 6, l = tid & 63;
    const int lg = l >> 4, lr = l & 15;
    const int wr = w >> 1, wc = w & 1;
    const int m0 = blockIdx.x * 128;
    const int n0 = blockIdx.y * 128;

    f32x4 acc[4][4];
    #pragma unroll
    for (int i = 0; i < 4; ++i)
        #pragma unroll
        for (int j = 0; j < 4; ++j) acc[i][j] = (f32x4){0.f, 0.f, 0.f, 0.f};

    gemm_core(Cb, Wob, Alds, Blds, acc, m0, n0, w, lg, lr);

    #pragma unroll
    for (int i = 0; i < 4; ++i) {
        const int mb = m0 + wr * 64 + 16 * i + 4 * lg;
        #pragma unroll
        for (int j = 0; j < 4; ++j) {
            const int ng = n0 + wc * 64 + 16 * j + lr;
            float* Yp = out + (size_t)mb * D_MODEL + ng;
            #pragma unroll
            for (int r = 0; r < 4; ++r)
                Yp[(size_t)r * D_MODEL] = acc[i][j][r];
        }
    }
}

// ---------------------------------------------------------------------------
// Flash attention (best-known, R10): bf16 MFMA, swapped QK^T, static-max
// softmax (logits ~N(0,1): 2^s never overflows f32; softmax scale-invariant),
// QBLK=256 (4 waves x 64 q-rows -- amortizes K/V DS traffic), KV-split x2,
// Plds round-trip PV, pad-68 conflict-free LDS.
// NOTE: sits on a register-occupancy cliff at ~120 VGPR (R14: +16 regs ->
// occupancy 18.9% -> 10.9%, flash +8 us).  Do not add live registers.
// ---------------------------------------------------------------------------
#define QBLK 256
#define KBLK 64

__global__ __launch_bounds__(256) void flash_mfma(
    const ushort* __restrict__ Q, const ushort* __restrict__ K,
    const ushort* __restrict__ Vt, ushort* __restrict__ Op,
    float* __restrict__ Ls)
{
    __shared__ __align__(16) ushort Klds[64][68];    // [key][dh]
    __shared__ __align__(16) ushort Vlds[64][68];    // [dh][key]
    __shared__ __align__(16) ushort Plds[256][68];   // [q][key]

    const int tid = threadIdx.x;
    const int w  = tid >> 6;
    const int l  = tid & 63;
    const int lg = l >> 4;
    const int lr = l & 15;

    const int bh = blockIdx.y;
    const int q0 = blockIdx.x * QBLK;
    const int z  = blockIdx.z;
    const int kt0 = z * KHALF;

    bf16x8 qa[4][2];
    #pragma unroll
    for (int u = 0; u < 4; ++u) {
        const ushort* qp = Q + ((size_t)bh * LSEQ + q0 + 64 * w + 16 * u + lr) * DH + 8 * lg;
        qa[u][0] = *(const bf16x8*)(qp);
        qa[u][1] = *(const bf16x8*)(qp + 32);
    }

    float lsum[4] = {0.f, 0.f, 0.f, 0.f};
    f32x4 o4[4][4];
    #pragma unroll
    for (int u = 0; u < 4; ++u)
        #pragma unroll
        for (int ot = 0; ot < 4; ++ot) o4[u][ot] = (f32x4){0.f, 0.f, 0.f, 0.f};

    const int srow = tid >> 2;            // 0..63
    const int scol = (tid & 3) << 4;      // 0,16,32,48
    const ushort* Kp = K  + (size_t)bh * LSEQ * DH;
    const ushort* Vp = Vt + (size_t)bh * DH * LSEQ;

    uint4 kA, kB, vA, vB;
    {
        const ushort* ks = Kp + (size_t)(kt0 + srow) * DH + scol;
        const ushort* vs = Vp + (size_t)srow * LSEQ + kt0 + scol;
        kA = *(const uint4*)(ks); kB = *(const uint4*)(ks + 8);
        vA = *(const uint4*)(vs); vB = *(const uint4*)(vs + 8);
    }

    for (int kt = kt0; kt < kt0 + KHALF; kt += KBLK) {
        __syncthreads();
        *(uint4*)&Klds[srow][scol] = kA;  *(uint4*)&Klds[srow][scol + 8] = kB;
        *(uint4*)&Vlds[srow][scol] = vA;  *(uint4*)&Vlds[srow][scol + 8] = vB;
        __syncthreads();

        if (kt + KBLK < kt0 + KHALF) {
            const ushort* ks = Kp + (size_t)(kt + KBLK + srow) * DH + scol;
            const ushort* vs = Vp + (size_t)srow * LSEQ + (kt + KBLK) + scol;
            kA = *(const uint4*)(ks); kB = *(const uint4*)(ks + 8);
            vA = *(const uint4*)(vs); vB = *(const uint4*)(vs + 8);
        }

        // ---- S^T = K Q^T : k-reads shared across the 4 q-subtiles ----
        f32x4 s[4][4];
        #pragma unroll
        for (int kt2 = 0; kt2 < 4; ++kt2) {
            bf16x8 k0 = *(const bf16x8*)&Klds[kt2 * 16 + lr][8 * lg];
            bf16x8 k1 = *(const bf16x8*)&Klds[kt2 * 16 + lr][32 + 8 * lg];
            #pragma unroll
            for (int u = 0; u < 4; ++u) {
                f32x4 z4 = (f32x4){0.f, 0.f, 0.f, 0.f};
                s[u][kt2] = MFMA16(k1, qa[u][1], MFMA16(k0, qa[u][0], z4));
            }
        }

        // ---- static-max softmax: p = 2^s; P -> Plds (bf16) ----
        #pragma unroll
        for (int u = 0; u < 4; ++u) {
            float rs = 0.f;
            #pragma unroll
            for (int kt2 = 0; kt2 < 4; ++kt2) {
                const float p0 = fexp2(s[u][kt2][0]);
                const float p1 = fexp2(s[u][kt2][1]);
                const float p2 = fexp2(s[u][kt2][2]);
                const float p3 = fexp2(s[u][kt2][3]);
                rs += (p0 + p1) + (p2 + p3);
                uint2 pw;
                pw.x = cvt_pk_bf16(p0, p1);
                pw.y = cvt_pk_bf16(p2, p3);
                *(uint2*)&Plds[64 * w + 16 * u + lr][kt2 * 16 + 4 * lg] = pw;
            }
            lsum[u] += rs;
        }

        // ---- O += P V : vv shared across the 4 q-subtiles ----
        #pragma unroll
        for (int vh = 0; vh < 2; ++vh) {
            bf16x8 pa[4];
            #pragma unroll
            for (int u = 0; u < 4; ++u)
                pa[u] = *(const bf16x8*)&Plds[64 * w + 16 * u + lr][32 * vh + 8 * lg];
            #pragma unroll
            for (int ot = 0; ot < 4; ++ot) {
                bf16x8 vv = *(const bf16x8*)&Vlds[16 * ot + lr][32 * vh + 8 * lg];
                #pragma unroll
                for (int u = 0; u < 4; ++u)
                    o4[u][ot] = MFMA16(pa[u], vv, o4[u][ot]);
            }
        }
    }

    // ---- epilogue: unnormalized bf16 O-partial + lsum ----
    const int b = bh >> 3, h = bh & 7;
    ushort* Opz = Op + (size_t)z * M_TOT * D_MODEL;
    #pragma unroll
    for (int u = 0; u < 4; ++u) {
        float t = lsum[u];
        t += __shfl_xor(t, 16);
        t += __shfl_xor(t, 32);
        if (lg == 0)   // lanes 0..15 hold the full row sums for q = lr
            Ls[((size_t)z * NB * NHEADS + bh) * LSEQ + q0 + 64 * w + 16 * u + lr] = t;
        #pragma unroll
        for (int r = 0; r < 4; ++r) {
            const int qrow = q0 + 64 * w + 16 * u + 4 * lg + r;
            ushort* op = Opz + ((size_t)b * LSEQ + qrow) * D_MODEL + h * DH + lr;
            #pragma unroll
            for (int ot = 0; ot < 4; ++ot)
                op[16 * ot] = f2bf(o4[u][ot][r]);
        }
    }
}

// ---------------------------------------------------------------------------
// Combine the two KV-split partials: Cb = (O0 + O1) / (l0 + l1), bf16.
// ---------------------------------------------------------------------------
__global__ __launch_bounds__(256) void combine(
    const ushort* __restrict__ Op, const float* __restrict__ Ls,
    ushort* __restrict__ Cb)
{
    const int idx = blockIdx.x * 256 + threadIdx.x;   // one 8-elem chunk
    const int row = idx >> 6;                         // 0..M_TOT-1
    const int col0 = (idx & 63) << 3;
    const int b = row >> 12, lq = row & 4095;
    const int h = col0 >> 6;
    const int bh = b * NHEADS + h;

    const float l0 = Ls[(size_t)bh * LSEQ + lq];
    const float l1 = Ls[((size_t)NB * NHEADS + bh) * LSEQ + lq];
    const float inv = 1.0f / (l0 + l1);

    const size_t off = (size_t)row * D_MODEL + col0;
    ushort8v a0 = *(const ushort8v*)(Op + off);
    ushort8v a1 = *(const ushort8v*)(Op + (size_t)M_TOT * D_MODEL + off);
    ushort8v o;
    #pragma unroll
    for (int i = 0; i < 8; ++i)
        o[i] = f2bf((bf2f(a0[i]) + bf2f(a1[i])) * inv);
    *(ushort8v*)(Cb + off) = o;
}

// ---------------------------------------------------------------------------
extern "C" void kernel_launch(void* const* d_in, const int* in_sizes, int n_in,
                              void* d_out, int out_size, void* d_ws, size_t ws_size,
                              hipStream_t stream)
{
    const float* X  = (const float*)d_in[0];
    const float* Wq = (const float*)d_in[1];
    const float* Wk = (const float*)d_in[2];
    const float* Wv = (const float*)d_in[3];
    const float* Wo = (const float*)d_in[4];
    float* out = (float*)d_out;

    char* ws = (char*)d_ws;
    const size_t szX = (size_t)M_TOT * D_MODEL * 2;       // 8.39 MB
    const size_t szW = (size_t)D_MODEL * D_MODEL * 2;     // 0.52 MB
    ushort* Xb  = (ushort*)(ws);
    ushort* Wqb = (ushort*)(ws + szX);
    ushort* Wkb = (ushort*)(ws + szX + szW);
    ushort* Wvb = (ushort*)(ws + szX + 2 * szW);
    ushort* Wob = (ushort*)(ws + szX + 3 * szW);
    ushort* Qb  = (ushort*)(ws + szX + 4 * szW);
    ushort* Kb  = (ushort*)(ws + 2 * szX + 4 * szW);
    ushort* Vtb = (ushort*)(ws + 3 * szX + 4 * szW);
    ushort* Opb = (ushort*)(ws + 4 * szX + 4 * szW);      // 2 x 8.39 MB
    float*  Lsb = (float*) (ws + 6 * szX + 4 * szW);      // 0.52 MB
    ushort* Cbb = (ushort*)(ws + 6 * szX + 4 * szW
                            + (size_t)NSPLIT * NB * NHEADS * LSEQ * 4);

    dim3 gc(M_TOT * D_MODEL / (256 * 8), 5);
    cast_all<<<gc, 256, 0, stream>>>(X, Wq, Wk, Wv, Wo, Xb, Wqb, Wkb, Wvb, Wob);

    dim3 gq(M_TOT / 128, D_MODEL / 128, 3);
    gemm_qkv<<<gq, 256, 0, stream>>>(Xb, Wqb, Wkb, Wvb, Qb, Kb, Vtb);

    dim3 gf(LSEQ / QBLK, NB * NHEADS, NSPLIT);
    flash_mfma<<<gf, 256, 0, stream>>>(Qb, Kb, Vtb, Opb, Lsb);

    dim3 gm(M_TOT * D_MODEL / (256 * 8));
    combine<<<gm, 256, 0, stream>>>(Opb, Lsb, Cbb);

    dim3 go(M_TOT / 128, D_MODEL / 128);
    gemm_wo<<<go, 256, 0, stream>>>(Cbb, Wob, out);
}

// Round 19
// 146.813 us; speedup vs baseline: 1.0699x; 1.0007x over previous
//
#include <hip/hip_runtime.h>
#include <math.h>

#define D_MODEL 512
#define NHEADS  8
#define DH      64
#define LSEQ    4096
#define NB      2
#define M_TOT   (NB * LSEQ)   // 8192
#define NSPLIT  2
#define KHALF   (LSEQ / NSPLIT)

typedef __attribute__((ext_vector_type(8))) short bf16x8;   // 8 bf16 = 4 VGPRs
typedef __attribute__((ext_vector_type(4))) float f32x4;
typedef __attribute__((ext_vector_type(8))) unsigned short ushort8v;

#define MFMA16(a, b, c) __builtin_amdgcn_mfma_f32_16x16x32_bf16(a, b, c, 0, 0, 0)

__device__ __forceinline__ ushort f2bf(float x) {
    unsigned u = __builtin_bit_cast(unsigned, x);
    u += 0x7fffu + ((u >> 16) & 1u);    // RNE
    return (ushort)(u >> 16);
}

__device__ __forceinline__ float bf2f(ushort u) {
    unsigned v = ((unsigned)u) << 16;
    return __builtin_bit_cast(float, v);
}

// packed f32x2 -> bf16x2 (lo = a, hi = b), single HW instruction, RNE
__device__ __forceinline__ unsigned cvt_pk_bf16(float a, float b) {
    unsigned r;
    asm("v_cvt_pk_bf16_f32 %0, %1, %2" : "=v"(r) : "v"(a), "v"(b));
    return r;
}

__device__ __forceinline__ float fexp2(float x) {
#if __has_builtin(__builtin_amdgcn_exp2f)
    return __builtin_amdgcn_exp2f(x);
#else
    return exp2f(x);
#endif
}

__device__ __forceinline__ void gload16(const void* g, void* l) {
    __builtin_amdgcn_global_load_lds(
        (const __attribute__((address_space(1))) unsigned*)g,
        (__attribute__((address_space(3))) unsigned*)l, 16, 0, 0);
}

// ---------------------------------------------------------------------------
// Cast fp32 -> bf16 (X and the four weight matrices).
// ---------------------------------------------------------------------------
__global__ __launch_bounds__(256) void cast_all(
    const float* __restrict__ X,  const float* __restrict__ Wq,
    const float* __restrict__ Wk, const float* __restrict__ Wv,
    const float* __restrict__ Wo,
    ushort* __restrict__ Xb,  ushort* __restrict__ Wqb,
    ushort* __restrict__ Wkb, ushort* __restrict__ Wvb,
    ushort* __restrict__ Wob)
{
    const int seg = blockIdx.y;
    const float* src = seg == 0 ? X : seg == 1 ? Wq : seg == 2 ? Wk
                      : seg == 3 ? Wv : Wo;
    ushort* dst = seg == 0 ? Xb : seg == 1 ? Wqb : seg == 2 ? Wkb
                 : seg == 3 ? Wvb : Wob;
    const int n = (seg == 0) ? M_TOT * D_MODEL : D_MODEL * D_MODEL;
    const int idx = (blockIdx.x * 256 + threadIdx.x) * 8;
    if (idx >= n) return;
    float4 a = *(const float4*)(src + idx);
    float4 b = *(const float4*)(src + idx + 4);
    ushort8v o;
    o[0] = f2bf(a.x); o[1] = f2bf(a.y); o[2] = f2bf(a.z); o[3] = f2bf(a.w);
    o[4] = f2bf(b.x); o[5] = f2bf(b.y); o[6] = f2bf(b.z); o[7] = f2bf(b.w);
    *(ushort8v*)(dst + idx) = o;
}

// ---------------------------------------------------------------------------
// bf16 MFMA GEMM, m97-style: BM=BN=128, BK=64, 4 waves (2x2), 2-barrier loop,
// global_load_lds width-16 staging, linear LDS.
// ---------------------------------------------------------------------------
__device__ __forceinline__ void gemm_core(
    const ushort* __restrict__ A, const ushort* __restrict__ Bw,
    ushort (*Alds)[64], ushort (*Blds)[64], f32x4 acc[4][4],
    int m0, int n0, int w, int lg, int lr)
{
    const int tid = threadIdx.x;
    const int wr = w >> 1, wc = w & 1;
    const int srow = tid >> 3;          // 0..31
    const int scol = (tid & 7) * 8;     // bf16 col (16B per lane)

    for (int k0 = 0; k0 < D_MODEL; k0 += 64) {
        __syncthreads();
        #pragma unroll
        for (int i = 0; i < 4; ++i) {
            gload16(A  + (size_t)(m0 + i * 32 + srow) * D_MODEL + k0 + scol,
                    (char*)Alds + i * 4096 + w * 1024);
            gload16(Bw + (size_t)(n0 + i * 32 + srow) * D_MODEL + k0 + scol,
                    (char*)Blds + i * 4096 + w * 1024);
        }
        __syncthreads();
        #pragma unroll
        for (int kk = 0; kk < 2; ++kk) {
            bf16x8 af[4], bfr[4];
            #pragma unroll
            for (int i = 0; i < 4; ++i)
                af[i] = *(const bf16x8*)&Alds[wr * 64 + 16 * i + lr][kk * 32 + 8 * lg];
            #pragma unroll
            for (int j = 0; j < 4; ++j)
                bfr[j] = *(const bf16x8*)&Blds[wc * 64 + 16 * j + lr][kk * 32 + 8 * lg];
            #pragma unroll
            for (int i = 0; i < 4; ++i)
                #pragma unroll
                for (int j = 0; j < 4; ++j)
                    acc[i][j] = MFMA16(af[i], bfr[j], acc[i][j]);
        }
    }
}

__global__ __launch_bounds__(256) void gemm_qkv(
    const ushort* __restrict__ Xb,
    const ushort* __restrict__ Wqb, const ushort* __restrict__ Wkb,
    const ushort* __restrict__ Wvb,
    ushort* __restrict__ Qb, ushort* __restrict__ Kb, ushort* __restrict__ Vtb)
{
    __shared__ __align__(16) ushort Alds[128][64];
    __shared__ __align__(16) ushort Blds[128][64];

    const int mode = blockIdx.z;
    const ushort* Bw = mode == 0 ? Wqb : mode == 1 ? Wkb : Wvb;

    const int tid = threadIdx.x;
    const int w = tid >> 6, l = tid & 63;
    const int lg = l >> 4, lr = l & 15;
    const int wr = w >> 1, wc = w & 1;
    const int m0 = blockIdx.x * 128;
    const int n0 = blockIdx.y * 128;

    f32x4 acc[4][4];
    #pragma unroll
    for (int i = 0; i < 4; ++i)
        #pragma unroll
        for (int j = 0; j < 4; ++j) acc[i][j] = (f32x4){0.f, 0.f, 0.f, 0.f};

    gemm_core(Xb, Bw, Alds, Blds, acc, m0, n0, w, lg, lr);

    if (mode < 2) {
        const float scale = (mode == 0) ? 0.125f * 1.44269504088896f : 1.0f;
        ushort* Yb = (mode == 0) ? Qb : Kb;
        #pragma unroll
        for (int i = 0; i < 4; ++i) {
            const int mb = m0 + wr * 64 + 16 * i + 4 * lg;
            const int b = mb >> 12, lq = mb & 4095;
            #pragma unroll
            for (int j = 0; j < 4; ++j) {
                const int ng = n0 + wc * 64 + 16 * j + lr;
                const int h = ng >> 6, dh = ng & 63;
                ushort* Yp = Yb + ((size_t)(b * NHEADS + h) * LSEQ + lq) * DH + dh;
                #pragma unroll
                for (int r = 0; r < 4; ++r)
                    Yp[(size_t)r * DH] = f2bf(acc[i][j][r] * scale);
            }
        }
    } else {
        #pragma unroll
        for (int i = 0; i < 4; ++i) {
            const int mb = m0 + wr * 64 + 16 * i + 4 * lg;
            const int b = mb >> 12, lq = mb & 4095;
            #pragma unroll
            for (int j = 0; j < 4; ++j) {
                const int ng = n0 + wc * 64 + 16 * j + lr;
                const int h = ng >> 6, dh = ng & 63;
                ushort4 w4;
                w4.x = f2bf(acc[i][j][0]); w4.y = f2bf(acc[i][j][1]);
                w4.z = f2bf(acc[i][j][2]); w4.w = f2bf(acc[i][j][3]);
                *(ushort4*)(Vtb + ((size_t)(b * NHEADS + h) * DH + dh) * LSEQ + lq) = w4;
            }
        }
    }
}

__global__ __launch_bounds__(256) void gemm_wo(
    const ushort* __restrict__ Cb, const ushort* __restrict__ Wob,
    float* __restrict__ out)
{
    __shared__ __align__(16) ushort Alds[128][64];
    __shared__ __align__(16) ushort Blds[128][64];

    const int tid = threadIdx.x;
    const int w = tid >> 6, l = tid & 63;
    const int lg = l >> 4, lr = l & 15;
    const int wr = w >> 1, wc = w & 1;
    const int m0 = blockIdx.x * 128;
    const int n0 = blockIdx.y * 128;

    f32x4 acc[4][4];
    #pragma unroll
    for (int i = 0; i < 4; ++i)
        #pragma unroll
        for (int j = 0; j < 4; ++j) acc[i][j] = (f32x4){0.f, 0.f, 0.f, 0.f};

    gemm_core(Cb, Wob, Alds, Blds, acc, m0, n0, w, lg, lr);

    #pragma unroll
    for (int i = 0; i < 4; ++i) {
        const int mb = m0 + wr * 64 + 16 * i + 4 * lg;
        #pragma unroll
        for (int j = 0; j < 4; ++j) {
            const int ng = n0 + wc * 64 + 16 * j + lr;
            float* Yp = out + (size_t)mb * D_MODEL + ng;
            #pragma unroll
            for (int r = 0; r < 4; ++r)
                Yp[(size_t)r * D_MODEL] = acc[i][j][r];
        }
    }
}

// ---------------------------------------------------------------------------
// Flash attention (best-known, R10/R15): bf16 MFMA, swapped QK^T, static-max
// softmax (logits ~N(0,1): 2^s never overflows f32; softmax scale-invariant),
// QBLK=256 (4 waves x 64 q-rows -- amortizes K/V DS traffic), KV-split x2,
// Plds round-trip PV, pad-68 conflict-free LDS.
// Session-verified constraints (do not violate):
//  - register cliff at ~120 VGPR + 64 AGPR: any added live regs -> 2->1
//    effective blocks overlap, +8 us (R14); __launch_bounds__(256,3) to force
//    3 waves/SIMD SILENTLY CORRUPTS RESULTS (R18) -- do not use.
//  - gload_lds + source-swizzle for K/V broke correctness (R16); in-register
//    PA variants broke correctness (R8/R9).  Keep ds-write staging + Plds.
// ---------------------------------------------------------------------------
#define QBLK 256
#define KBLK 64

__global__ __launch_bounds__(256) void flash_mfma(
    const ushort* __restrict__ Q, const ushort* __restrict__ K,
    const ushort* __restrict__ Vt, ushort* __restrict__ Op,
    float* __restrict__ Ls)
{
    __shared__ __align__(16) ushort Klds[64][68];    // [key][dh]
    __shared__ __align__(16) ushort Vlds[64][68];    // [dh][key]
    __shared__ __align__(16) ushort Plds[256][68];   // [q][key]

    const int tid = threadIdx.x;
    const int w  = tid >> 6;
    const int l  = tid & 63;
    const int lg = l >> 4;
    const int lr = l & 15;

    const int bh = blockIdx.y;
    const int q0 = blockIdx.x * QBLK;
    const int z  = blockIdx.z;
    const int kt0 = z * KHALF;

    bf16x8 qa[4][2];
    #pragma unroll
    for (int u = 0; u < 4; ++u) {
        const ushort* qp = Q + ((size_t)bh * LSEQ + q0 + 64 * w + 16 * u + lr) * DH + 8 * lg;
        qa[u][0] = *(const bf16x8*)(qp);
        qa[u][1] = *(const bf16x8*)(qp + 32);
    }

    float lsum[4] = {0.f, 0.f, 0.f, 0.f};
    f32x4 o4[4][4];
    #pragma unroll
    for (int u = 0; u < 4; ++u)
        #pragma unroll
        for (int ot = 0; ot < 4; ++ot) o4[u][ot] = (f32x4){0.f, 0.f, 0.f, 0.f};

    const int srow = tid >> 2;            // 0..63
    const int scol = (tid & 3) << 4;      // 0,16,32,48
    const ushort* Kp = K  + (size_t)bh * LSEQ * DH;
    const ushort* Vp = Vt + (size_t)bh * DH * LSEQ;

    uint4 kA, kB, vA, vB;
    {
        const ushort* ks = Kp + (size_t)(kt0 + srow) * DH + scol;
        const ushort* vs = Vp + (size_t)srow * LSEQ + kt0 + scol;
        kA = *(const uint4*)(ks); kB = *(const uint4*)(ks + 8);
        vA = *(const uint4*)(vs); vB = *(const uint4*)(vs + 8);
    }

    for (int kt = kt0; kt < kt0 + KHALF; kt += KBLK) {
        __syncthreads();
        *(uint4*)&Klds[srow][scol] = kA;  *(uint4*)&Klds[srow][scol + 8] = kB;
        *(uint4*)&Vlds[srow][scol] = vA;  *(uint4*)&Vlds[srow][scol + 8] = vB;
        __syncthreads();

        if (kt + KBLK < kt0 + KHALF) {
            const ushort* ks = Kp + (size_t)(kt + KBLK + srow) * DH + scol;
            const ushort* vs = Vp + (size_t)srow * LSEQ + (kt + KBLK) + scol;
            kA = *(const uint4*)(ks); kB = *(const uint4*)(ks + 8);
            vA = *(const uint4*)(vs); vB = *(const uint4*)(vs + 8);
        }

        // ---- S^T = K Q^T : k-reads shared across the 4 q-subtiles ----
        f32x4 s[4][4];
        #pragma unroll
        for (int kt2 = 0; kt2 < 4; ++kt2) {
            bf16x8 k0 = *(const bf16x8*)&Klds[kt2 * 16 + lr][8 * lg];
            bf16x8 k1 = *(const bf16x8*)&Klds[kt2 * 16 + lr][32 + 8 * lg];
            #pragma unroll
            for (int u = 0; u < 4; ++u) {
                f32x4 z4 = (f32x4){0.f, 0.f, 0.f, 0.f};
                s[u][kt2] = MFMA16(k1, qa[u][1], MFMA16(k0, qa[u][0], z4));
            }
        }

        // ---- static-max softmax: p = 2^s; P -> Plds (bf16) ----
        #pragma unroll
        for (int u = 0; u < 4; ++u) {
            float rs = 0.f;
            #pragma unroll
            for (int kt2 = 0; kt2 < 4; ++kt2) {
                const float p0 = fexp2(s[u][kt2][0]);
                const float p1 = fexp2(s[u][kt2][1]);
                const float p2 = fexp2(s[u][kt2][2]);
                const float p3 = fexp2(s[u][kt2][3]);
                rs += (p0 + p1) + (p2 + p3);
                uint2 pw;
                pw.x = cvt_pk_bf16(p0, p1);
                pw.y = cvt_pk_bf16(p2, p3);
                *(uint2*)&Plds[64 * w + 16 * u + lr][kt2 * 16 + 4 * lg] = pw;
            }
            lsum[u] += rs;
        }

        // ---- O += P V : vv shared across the 4 q-subtiles ----
        #pragma unroll
        for (int vh = 0; vh < 2; ++vh) {
            bf16x8 pa[4];
            #pragma unroll
            for (int u = 0; u < 4; ++u)
                pa[u] = *(const bf16x8*)&Plds[64 * w + 16 * u + lr][32 * vh + 8 * lg];
            #pragma unroll
            for (int ot = 0; ot < 4; ++ot) {
                bf16x8 vv = *(const bf16x8*)&Vlds[16 * ot + lr][32 * vh + 8 * lg];
                #pragma unroll
                for (int u = 0; u < 4; ++u)
                    o4[u][ot] = MFMA16(pa[u], vv, o4[u][ot]);
            }
        }
    }

    // ---- epilogue: unnormalized bf16 O-partial + lsum ----
    const int b = bh >> 3, h = bh & 7;
    ushort* Opz = Op + (size_t)z * M_TOT * D_MODEL;
    #pragma unroll
    for (int u = 0; u < 4; ++u) {
        float t = lsum[u];
        t += __shfl_xor(t, 16);
        t += __shfl_xor(t, 32);
        if (lg == 0)   // lanes 0..15 hold the full row sums for q = lr
            Ls[((size_t)z * NB * NHEADS + bh) * LSEQ + q0 + 64 * w + 16 * u + lr] = t;
        #pragma unroll
        for (int r = 0; r < 4; ++r) {
            const int qrow = q0 + 64 * w + 16 * u + 4 * lg + r;
            ushort* op = Opz + ((size_t)b * LSEQ + qrow) * D_MODEL + h * DH + lr;
            #pragma unroll
            for (int ot = 0; ot < 4; ++ot)
                op[16 * ot] = f2bf(o4[u][ot][r]);
        }
    }
}

// ---------------------------------------------------------------------------
// Combine the two KV-split partials: Cb = (O0 + O1) / (l0 + l1), bf16.
// ---------------------------------------------------------------------------
__global__ __launch_bounds__(256) void combine(
    const ushort* __restrict__ Op, const float* __restrict__ Ls,
    ushort* __restrict__ Cb)
{
    const int idx = blockIdx.x * 256 + threadIdx.x;   // one 8-elem chunk
    const int row = idx >> 6;                         // 0..M_TOT-1
    const int col0 = (idx & 63) << 3;
    const int b = row >> 12, lq = row & 4095;
    const int h = col0 >> 6;
    const int bh = b * NHEADS + h;

    const float l0 = Ls[(size_t)bh * LSEQ + lq];
    const float l1 = Ls[((size_t)NB * NHEADS + bh) * LSEQ + lq];
    const float inv = 1.0f / (l0 + l1);

    const size_t off = (size_t)row * D_MODEL + col0;
    ushort8v a0 = *(const ushort8v*)(Op + off);
    ushort8v a1 = *(const ushort8v*)(Op + (size_t)M_TOT * D_MODEL + off);
    ushort8v o;
    #pragma unroll
    for (int i = 0; i < 8; ++i)
        o[i] = f2bf((bf2f(a0[i]) + bf2f(a1[i])) * inv);
    *(ushort8v*)(Cb + off) = o;
}

// ---------------------------------------------------------------------------
extern "C" void kernel_launch(void* const* d_in, const int* in_sizes, int n_in,
                              void* d_out, int out_size, void* d_ws, size_t ws_size,
                              hipStream_t stream)
{
    const float* X  = (const float*)d_in[0];
    const float* Wq = (const float*)d_in[1];
    const float* Wk = (const float*)d_in[2];
    const float* Wv = (const float*)d_in[3];
    const float* Wo = (const float*)d_in[4];
    float* out = (float*)d_out;

    char* ws = (char*)d_ws;
    const size_t szX = (size_t)M_TOT * D_MODEL * 2;       // 8.39 MB
    const size_t szW = (size_t)D_MODEL * D_MODEL * 2;     // 0.52 MB
    ushort* Xb  = (ushort*)(ws);
    ushort* Wqb = (ushort*)(ws + szX);
    ushort* Wkb = (ushort*)(ws + szX + szW);
    ushort* Wvb = (ushort*)(ws + szX + 2 * szW);
    ushort* Wob = (ushort*)(ws + szX + 3 * szW);
    ushort* Qb  = (ushort*)(ws + szX + 4 * szW);
    ushort* Kb  = (ushort*)(ws + 2 * szX + 4 * szW);
    ushort* Vtb = (ushort*)(ws + 3 * szX + 4 * szW);
    ushort* Opb = (ushort*)(ws + 4 * szX + 4 * szW);      // 2 x 8.39 MB
    float*  Lsb = (float*) (ws + 6 * szX + 4 * szW);      // 0.52 MB
    ushort* Cbb = (ushort*)(ws + 6 * szX + 4 * szW
                            + (size_t)NSPLIT * NB * NHEADS * LSEQ * 4);

    dim3 gc(M_TOT * D_MODEL / (256 * 8), 5);
    cast_all<<<gc, 256, 0, stream>>>(X, Wq, Wk, Wv, Wo, Xb, Wqb, Wkb, Wvb, Wob);

    dim3 gq(M_TOT / 128, D_MODEL / 128, 3);
    gemm_qkv<<<gq, 256, 0, stream>>>(Xb, Wqb, Wkb, Wvb, Qb, Kb, Vtb);

    dim3 gf(LSEQ / QBLK, NB * NHEADS, NSPLIT);
    flash_mfma<<<gf, 256, 0, stream>>>(Qb, Kb, Vtb, Opb, Lsb);

    dim3 gm(M_TOT * D_MODEL / (256 * 8));
    combine<<<gm, 256, 0, stream>>>(Opb, Lsb, Cbb);

    dim3 go(M_TOT / 128, D_MODEL / 128);
    gemm_wo<<<go, 256, 0, stream>>>(Cbb, Wob, out);
}